// Round 6
// baseline (40.741 us; speedup 1.0000x reference)
//
#include <hip/hip_runtime.h>
#include <math.h>

// Problem: x[B=32][N=2048][K=8], W[N][C=32][J=16][K=8], R[N][C]
// out[b][c][j] = squash_j( sum_n softmax_n(R)[n,c] * sum_k W[n,c,j,k]*x[b,n,k] )

#define NN 2048
#define CC 32

__device__ __forceinline__ void g2l16(const float* g, float* l) {
  __builtin_amdgcn_global_load_lds((const __attribute__((address_space(1))) void*)g,
                                   (__attribute__((address_space(3))) void*)l, 16, 0, 0);
}

// Kernel 1: fused softmax-stats + contraction.
// grid 512: chunk = bid&63 (32 n), cq = bid>>6 (4 c's). XCD = bid%8 = chunk%8, so all
// 8 cq-blocks of a chunk share an XCD -> x slice L2-resident (fetched once per chunk).
// block 512 = 8 waves; 64KB LDS -> 2 blocks/CU; VGPR budget pinned via waves_per_eu(4,4).
// Wave ws does n = n0 + s*8 + ws, s<4. lane: j = lane&15, bo = lane>>4.
// Thread tile acc[ci 4][bi 8]; b = bo*8+bi, c = cq*4+ci.
// LDS: ldsW[2][4096]f (8-n W slabs; per n 128 granules, slot = g ^ (j>>1) swizzle,
//      inverse applied on staging source), ldsX[32][256]f ([n][k 8][b 32], reg-staged).
__global__ __launch_bounds__(512) __attribute__((amdgpu_waves_per_eu(4, 4)))
void caps_main(const float* __restrict__ x, const float* __restrict__ W,
               const float* __restrict__ R, float* __restrict__ P) {
  const int bid = blockIdx.x;
  const int cq = bid >> 6;
  const int chunk = bid & 63;
  const int n0 = chunk * 32;
  const int tid = threadIdx.x;
  const int ws = tid >> 6;
  const int lane = tid & 63;
  const int j = lane & 15;
  const int bo = lane >> 4;

  extern __shared__ float smem[];
  float* ldsW = smem;          // [2][4096] floats (32KB)
  float* ldsX = smem + 8192;   // [32][256] floats (32KB)
  float* red8 = smem + 4096;   // 32 floats inside slab1 (dead until s=0 prefetch)

  // ---- prologue: async-stage W slab 0 (16KB). LDS slot S <- source granule
  // g = S ^ (((S>>2)^(S>>4))&1) ^ (((S>>3)&1)<<1) ^ (((S>>4)&1)<<2)  [inverse of ^(j>>1)]
#pragma unroll
  for (int it = 0; it < 2; ++it) {
    int idx = it * 512 + tid;
    int nl = idx >> 7, S = idx & 127;
    int g = S ^ (((S >> 2) ^ (S >> 4)) & 1) ^ (((S >> 3) & 1) << 1) ^ (((S >> 4) & 1) << 2);
    g2l16(W + (size_t)(n0 + nl) * 4096 + cq * 512 + g * 4,
          ldsW + (size_t)(it * 512 + ws * 64) * 4);
  }

  // ---- reg-stage x into [n][k][b] (k<->b transpose; g2l16 can't) ----
  float4 xg[4];
  int xoff[4];
#pragma unroll
  for (int it = 0; it < 4; ++it) {
    int idx = it * 512 + tid;
    int nl = idx >> 6, r = idx & 63;
    int b = r & 31, kq = r >> 5;
    xg[it] = *(const float4*)(x + (size_t)b * (NN * 8) + (size_t)(n0 + nl) * 8 + kq * 4);
    xoff[it] = nl * 256 + kq * 128 + b;
  }
#pragma unroll
  for (int it = 0; it < 4; ++it) {
    float* d = ldsX + xoff[it];
    d[0] = xg[it].x; d[32] = xg[it].y; d[64] = xg[it].z; d[96] = xg[it].w;
  }

  // ---- phase 0 (overlaps staging): softmax denominators for this c-quad ----
  float se[4] = {0.f, 0.f, 0.f, 0.f};
#pragma unroll
  for (int i = 0; i < 4; ++i) {
    int n = i * 512 + tid;
    float4 a = *(const float4*)(R + (size_t)n * CC + cq * 4);
    se[0] += expf(a.x); se[1] += expf(a.y); se[2] += expf(a.z); se[3] += expf(a.w);
  }
#pragma unroll
  for (int ci = 0; ci < 4; ++ci) {
    float v = se[ci];
#pragma unroll
    for (int d = 32; d >= 1; d >>= 1) v += __shfl_xor(v, d, 64);
    se[ci] = v;
  }
  if (lane == 0) {
#pragma unroll
    for (int ci = 0; ci < 4; ++ci) red8[ws * 4 + ci] = se[ci];
  }
  __syncthreads();  // drains W slab0 g2l16 + x ds_writes too

  float inv4[4];
  {
    float t[4] = {0.f, 0.f, 0.f, 0.f};
#pragma unroll
    for (int w = 0; w < 8; ++w)
#pragma unroll
      for (int ci = 0; ci < 4; ++ci) t[ci] += red8[w * 4 + ci];
#pragma unroll
    for (int ci = 0; ci < 4; ++ci) inv4[ci] = 1.0f / t[ci];
  }
  __syncthreads();  // red8 consumed before slab-1 prefetch overwrites it

  float acc[4][8];
#pragma unroll
  for (int a = 0; a < 4; ++a)
#pragma unroll
    for (int b = 0; b < 8; ++b) acc[a][b] = 0.f;

  const int jsw = j >> 1;  // read-side W swizzle mask

#pragma unroll 1
  for (int s = 0; s < 4; ++s) {
    if (s < 3) {
      const int sb = n0 + (s + 1) * 8;
      float* wdst = ldsW + (size_t)((s + 1) & 1) * 4096;
#pragma unroll
      for (int it = 0; it < 2; ++it) {
        int idx = it * 512 + tid;
        int nl = idx >> 7, S = idx & 127;
        int g = S ^ (((S >> 2) ^ (S >> 4)) & 1) ^ (((S >> 3) & 1) << 1) ^ (((S >> 4) & 1) << 2);
        g2l16(W + (size_t)(sb + nl) * 4096 + cq * 512 + g * 4,
              wdst + (size_t)(it * 512 + ws * 64) * 4);
      }
    }
    const int n = n0 + s * 8 + ws;
    const float* Xn = ldsX + (size_t)(s * 8 + ws) * 256;
    const float* Wn = ldsW + (size_t)(s & 1) * 4096 + (size_t)ws * 512;

    const float* rr = R + (size_t)n * CC + cq * 4;  // wave-uniform, L2-hit
    float rv[4];
#pragma unroll
    for (int ci = 0; ci < 4; ++ci) rv[ci] = expf(rr[ci]) * inv4[ci];

#pragma unroll
    for (int kh = 0; kh < 2; ++kh) {
      // x columns for this k-half: 32 regs, conflict-free reads
      float4 xlo[4], xhi[4];
#pragma unroll
      for (int kk = 0; kk < 4; ++kk) {
        const float* xp = Xn + (kh * 4 + kk) * 32 + bo * 8;
        xlo[kk] = *(const float4*)xp;
        xhi[kk] = *(const float4*)(xp + 4);
      }
#pragma unroll
      for (int ci = 0; ci < 4; ++ci) {
        int slot = (ci * 32 + j * 2 + kh) ^ jsw;
        float4 wf = *(const float4*)(Wn + slot * 4);
        float rvv = rv[ci];
        float w0 = wf.x * rvv, w1 = wf.y * rvv, w2 = wf.z * rvv, w3 = wf.w * rvv;
        float a0, a1;
#pragma unroll
        for (int bi = 0; bi < 4; ++bi) {
          a0 = acc[ci][bi];
          a0 = fmaf(w0, (&xlo[0].x)[bi], a0);
          a0 = fmaf(w1, (&xlo[1].x)[bi], a0);
          a0 = fmaf(w2, (&xlo[2].x)[bi], a0);
          a0 = fmaf(w3, (&xlo[3].x)[bi], a0);
          acc[ci][bi] = a0;
          a1 = acc[ci][bi + 4];
          a1 = fmaf(w0, (&xhi[0].x)[bi], a1);
          a1 = fmaf(w1, (&xhi[1].x)[bi], a1);
          a1 = fmaf(w2, (&xhi[2].x)[bi], a1);
          a1 = fmaf(w3, (&xhi[3].x)[bi], a1);
          acc[ci][bi + 4] = a1;
        }
      }
    }
    __syncthreads();
  }

  // ---- single-stage cross-wave reduction: whole 64KB LDS is dead now ----
  // wave ws dumps acc at ldsAll[ws*2048 + cell], cell = (ci*8+bi)*64 + lane.
  float* ldsAll = smem;
#pragma unroll
  for (int ci = 0; ci < 4; ++ci)
#pragma unroll
    for (int bi = 0; bi < 8; ++bi)
      ldsAll[(size_t)ws * 2048 + (ci * 8 + bi) * 64 + lane] = acc[ci][bi];
  __syncthreads();

  // thread t sums cells 4t..4t+3 over 8 waves (8x ds_read_b128), coalesced P write
  {
    const int t4 = tid * 4;
    float4 ssum = make_float4(0.f, 0.f, 0.f, 0.f);
#pragma unroll
    for (int w = 0; w < 8; ++w) {
      float4 v = *(const float4*)(ldsAll + (size_t)w * 2048 + t4);
      ssum.x += v.x; ssum.y += v.y; ssum.z += v.z; ssum.w += v.w;
    }
    *(float4*)(P + (size_t)bid * 2048 + t4) = ssum;
  }
}

// Kernel 2: cross-chunk reduce + squash. 64 blocks x 256 threads.
// P[bid=cq*64+ch][cell=(ci*8+bi)*64 + bo*16 + j]
__global__ void caps_reduce(const float* __restrict__ P, float* __restrict__ out) {
  const int g = blockIdx.x * 256 + threadIdx.x;  // b*512 + c*16 + j
  const int j = g & 15;
  const int c = (g >> 4) & 31;
  const int b = g >> 9;
  const int bo = b >> 3, bi = b & 7;
  const int cq = c >> 2, ci = c & 3;
  const int idx = (ci * 8 + bi) * 64 + (bo * 16 + j);
  const float* Pq = P + (size_t)cq * 64 * 2048 + idx;

  float s = 0.f;
#pragma unroll 16
  for (int ch = 0; ch < 64; ++ch) {
    s += Pq[(size_t)ch * 2048];
  }
  float sq = s * s;
  sq += __shfl_xor(sq, 8, 16);
  sq += __shfl_xor(sq, 4, 16);
  sq += __shfl_xor(sq, 2, 16);
  sq += __shfl_xor(sq, 1, 16);
  float ss = sq + 1e-7f;
  float scale = sqrtf(ss) / (1.0f + ss);
  out[g] = scale * s;
}

extern "C" void kernel_launch(void* const* d_in, const int* in_sizes, int n_in,
                              void* d_out, int out_size, void* d_ws, size_t ws_size,
                              hipStream_t stream) {
  const float* x = (const float*)d_in[0];   // 32*2048*8
  const float* W = (const float*)d_in[1];   // 2048*32*16*8
  const float* R = (const float*)d_in[2];   // 2048*32
  float* out = (float*)d_out;               // 32*32*16
  float* P = (float*)d_ws;                  // 512*2048 floats (4 MB)

  hipFuncSetAttribute((const void*)caps_main,
                      hipFuncAttributeMaxDynamicSharedMemorySize, 65536);

  caps_main<<<512, 512, 65536, stream>>>(x, W, R, P);
  caps_reduce<<<64, 256, 0, stream>>>(P, out);
}

// Round 7
// 28.019 us; speedup vs baseline: 1.4540x; 1.4540x over previous
//
#include <hip/hip_runtime.h>
#include <math.h>

// Problem: x[B=32][N=2048][K=8], W[N][C=32][J=16][K=8], R[N][C]
// out[b][c][j] = squash_j( sum_n softmax_n(R)[n,c] * sum_k W[n,c,j,k]*x[b,n,k] )

#define NN 2048
#define CC 32

__device__ __forceinline__ void g2l16(const float* g, float* l) {
  __builtin_amdgcn_global_load_lds((const __attribute__((address_space(1))) void*)g,
                                   (__attribute__((address_space(3))) void*)l, 16, 0, 0);
}

// Kernel 1: fused softmax-stats + contraction.
// grid 512: chunk = bid&63 (32 n), cq = bid>>6 (4 c's). XCD = bid%8 = chunk%8, so all
// 8 cq-blocks of a chunk share an XCD -> x slice L2-resident (fetched once per chunk).
// block 512 = 8 waves; 64KB LDS -> 2 blocks/CU. NO occupancy attribute: measured
// (R4/R6) that waves_per_eu/launch_bounds hints clamp VGPR to 64 and spill ~60MB;
// unconstrained (R3) the allocator picks ~104 VGPR, zero spill, still 16 waves/CU.
// Wave ws does n = n0 + s*8 + ws, s<4. lane: j = lane&15, bo = lane>>4.
// Thread tile acc[ci 4][bi 8]; b = bo*8+bi, c = cq*4+ci.
// LDS: ldsW[2][4096]f (8-n W slabs; per n 128 granules, slot = g ^ (j>>1) swizzle,
//      inverse applied on staging source), ldsX[32][256]f ([n][k 8][b 32], reg-staged).
__global__ void __launch_bounds__(512) caps_main(const float* __restrict__ x,
                                                 const float* __restrict__ W,
                                                 const float* __restrict__ R,
                                                 float* __restrict__ P) {
  const int bid = blockIdx.x;
  const int cq = bid >> 6;
  const int chunk = bid & 63;
  const int n0 = chunk * 32;
  const int tid = threadIdx.x;
  const int ws = tid >> 6;
  const int lane = tid & 63;
  const int j = lane & 15;
  const int bo = lane >> 4;

  extern __shared__ float smem[];
  float* ldsW = smem;          // [2][4096] floats (32KB)
  float* ldsX = smem + 8192;   // [32][256] floats (32KB)
  float* red8 = smem + 4096;   // 32 floats inside slab1 (dead until s=0 prefetch)

  // ---- prologue: async-stage W slab 0 (16KB). LDS slot S <- source granule
  // g = S ^ (((S>>2)^(S>>4))&1) ^ (((S>>3)&1)<<1) ^ (((S>>4)&1)<<2)  [inverse of ^(j>>1)]
#pragma unroll
  for (int it = 0; it < 2; ++it) {
    int idx = it * 512 + tid;
    int nl = idx >> 7, S = idx & 127;
    int g = S ^ (((S >> 2) ^ (S >> 4)) & 1) ^ (((S >> 3) & 1) << 1) ^ (((S >> 4) & 1) << 2);
    g2l16(W + (size_t)(n0 + nl) * 4096 + cq * 512 + g * 4,
          ldsW + (size_t)(it * 512 + ws * 64) * 4);
  }

  // ---- reg-stage x into [n][k][b] (k<->b transpose; g2l16 can't) ----
  float4 xg[4];
  int xoff[4];
#pragma unroll
  for (int it = 0; it < 4; ++it) {
    int idx = it * 512 + tid;
    int nl = idx >> 6, r = idx & 63;
    int b = r & 31, kq = r >> 5;
    xg[it] = *(const float4*)(x + (size_t)b * (NN * 8) + (size_t)(n0 + nl) * 8 + kq * 4);
    xoff[it] = nl * 256 + kq * 128 + b;
  }
#pragma unroll
  for (int it = 0; it < 4; ++it) {
    float* d = ldsX + xoff[it];
    d[0] = xg[it].x; d[32] = xg[it].y; d[64] = xg[it].z; d[96] = xg[it].w;
  }

  // ---- phase 0 (overlaps staging): softmax denominators for this c-quad ----
  float se[4] = {0.f, 0.f, 0.f, 0.f};
#pragma unroll
  for (int i = 0; i < 4; ++i) {
    int n = i * 512 + tid;
    float4 a = *(const float4*)(R + (size_t)n * CC + cq * 4);
    se[0] += expf(a.x); se[1] += expf(a.y); se[2] += expf(a.z); se[3] += expf(a.w);
  }
#pragma unroll
  for (int ci = 0; ci < 4; ++ci) {
    float v = se[ci];
#pragma unroll
    for (int d = 32; d >= 1; d >>= 1) v += __shfl_xor(v, d, 64);
    se[ci] = v;
  }
  if (lane == 0) {
#pragma unroll
    for (int ci = 0; ci < 4; ++ci) red8[ws * 4 + ci] = se[ci];
  }
  __syncthreads();  // drains W slab0 g2l16 + x ds_writes too

  float inv4[4];
  {
    float t[4] = {0.f, 0.f, 0.f, 0.f};
#pragma unroll
    for (int w = 0; w < 8; ++w)
#pragma unroll
      for (int ci = 0; ci < 4; ++ci) t[ci] += red8[w * 4 + ci];
#pragma unroll
    for (int ci = 0; ci < 4; ++ci) inv4[ci] = 1.0f / t[ci];
  }
  __syncthreads();  // red8 consumed before slab-1 prefetch overwrites it

  float acc[4][8];
#pragma unroll
  for (int a = 0; a < 4; ++a)
#pragma unroll
    for (int b = 0; b < 8; ++b) acc[a][b] = 0.f;

  const int jsw = j >> 1;  // read-side W swizzle mask

#pragma unroll 1
  for (int s = 0; s < 4; ++s) {
    if (s < 3) {
      const int sb = n0 + (s + 1) * 8;
      float* wdst = ldsW + (size_t)((s + 1) & 1) * 4096;
#pragma unroll
      for (int it = 0; it < 2; ++it) {
        int idx = it * 512 + tid;
        int nl = idx >> 7, S = idx & 127;
        int g = S ^ (((S >> 2) ^ (S >> 4)) & 1) ^ (((S >> 3) & 1) << 1) ^ (((S >> 4) & 1) << 2);
        g2l16(W + (size_t)(sb + nl) * 4096 + cq * 512 + g * 4,
              wdst + (size_t)(it * 512 + ws * 64) * 4);
      }
    }
    const int n = n0 + s * 8 + ws;
    const float* Xn = ldsX + (size_t)(s * 8 + ws) * 256;
    const float* Wn = ldsW + (size_t)(s & 1) * 4096 + (size_t)ws * 512;

    const float* rr = R + (size_t)n * CC + cq * 4;  // wave-uniform, L2-hit
    float rv[4];
#pragma unroll
    for (int ci = 0; ci < 4; ++ci) rv[ci] = expf(rr[ci]) * inv4[ci];

#pragma unroll
    for (int kh = 0; kh < 2; ++kh) {
      // x columns for this k-half: 32 regs, conflict-free reads
      float4 xlo[4], xhi[4];
#pragma unroll
      for (int kk = 0; kk < 4; ++kk) {
        const float* xp = Xn + (kh * 4 + kk) * 32 + bo * 8;
        xlo[kk] = *(const float4*)xp;
        xhi[kk] = *(const float4*)(xp + 4);
      }
#pragma unroll
      for (int ci = 0; ci < 4; ++ci) {
        int slot = (ci * 32 + j * 2 + kh) ^ jsw;
        float4 wf = *(const float4*)(Wn + slot * 4);
        float rvv = rv[ci];
        float w0 = wf.x * rvv, w1 = wf.y * rvv, w2 = wf.z * rvv, w3 = wf.w * rvv;
        float a0, a1;
#pragma unroll
        for (int bi = 0; bi < 4; ++bi) {
          a0 = acc[ci][bi];
          a0 = fmaf(w0, (&xlo[0].x)[bi], a0);
          a0 = fmaf(w1, (&xlo[1].x)[bi], a0);
          a0 = fmaf(w2, (&xlo[2].x)[bi], a0);
          a0 = fmaf(w3, (&xlo[3].x)[bi], a0);
          acc[ci][bi] = a0;
          a1 = acc[ci][bi + 4];
          a1 = fmaf(w0, (&xhi[0].x)[bi], a1);
          a1 = fmaf(w1, (&xhi[1].x)[bi], a1);
          a1 = fmaf(w2, (&xhi[2].x)[bi], a1);
          a1 = fmaf(w3, (&xhi[3].x)[bi], a1);
          acc[ci][bi + 4] = a1;
        }
      }
    }
    __syncthreads();
  }

  // ---- single-stage cross-wave reduction: whole 64KB LDS is dead now ----
  float* ldsAll = smem;
#pragma unroll
  for (int ci = 0; ci < 4; ++ci)
#pragma unroll
    for (int bi = 0; bi < 8; ++bi)
      ldsAll[(size_t)ws * 2048 + (ci * 8 + bi) * 64 + lane] = acc[ci][bi];
  __syncthreads();

  // thread t sums cells 4t..4t+3 over 8 waves (8x ds_read_b128), coalesced P write
  {
    const int t4 = tid * 4;
    float4 ssum = make_float4(0.f, 0.f, 0.f, 0.f);
#pragma unroll
    for (int w = 0; w < 8; ++w) {
      float4 v = *(const float4*)(ldsAll + (size_t)w * 2048 + t4);
      ssum.x += v.x; ssum.y += v.y; ssum.z += v.z; ssum.w += v.w;
    }
    *(float4*)(P + (size_t)bid * 2048 + t4) = ssum;
  }
}

// Kernel 2: cross-chunk reduce + squash. 64 blocks x 256 threads.
// P[bid=cq*64+ch][cell=(ci*8+bi)*64 + bo*16 + j]
__global__ void caps_reduce(const float* __restrict__ P, float* __restrict__ out) {
  const int g = blockIdx.x * 256 + threadIdx.x;  // b*512 + c*16 + j
  const int j = g & 15;
  const int c = (g >> 4) & 31;
  const int b = g >> 9;
  const int bo = b >> 3, bi = b & 7;
  const int cq = c >> 2, ci = c & 3;
  const int idx = (ci * 8 + bi) * 64 + (bo * 16 + j);
  const float* Pq = P + (size_t)cq * 64 * 2048 + idx;

  float s = 0.f;
#pragma unroll 16
  for (int ch = 0; ch < 64; ++ch) {
    s += Pq[(size_t)ch * 2048];
  }
  float sq = s * s;
  sq += __shfl_xor(sq, 8, 16);
  sq += __shfl_xor(sq, 4, 16);
  sq += __shfl_xor(sq, 2, 16);
  sq += __shfl_xor(sq, 1, 16);
  float ss = sq + 1e-7f;
  float scale = sqrtf(ss) / (1.0f + ss);
  out[g] = scale * s;
}

extern "C" void kernel_launch(void* const* d_in, const int* in_sizes, int n_in,
                              void* d_out, int out_size, void* d_ws, size_t ws_size,
                              hipStream_t stream) {
  const float* x = (const float*)d_in[0];   // 32*2048*8
  const float* W = (const float*)d_in[1];   // 2048*32*16*8
  const float* R = (const float*)d_in[2];   // 2048*32
  float* out = (float*)d_out;               // 32*32*16
  float* P = (float*)d_ws;                  // 512*2048 floats (4 MB)

  hipFuncSetAttribute((const void*)caps_main,
                      hipFuncAttributeMaxDynamicSharedMemorySize, 65536);

  caps_main<<<512, 512, 65536, stream>>>(x, W, R, P);
  caps_reduce<<<64, 256, 0, stream>>>(P, out);
}

// Round 8
// 26.928 us; speedup vs baseline: 1.5130x; 1.0405x over previous
//
#include <hip/hip_runtime.h>
#include <math.h>

// Problem: x[B=32][N=2048][K=8], W[N][C=32][J=16][K=8], R[N][C]
// out[b][c][j] = squash_j( sum_n softmax_n(R)[n,c] * sum_k W[n,c,j,k]*x[b,n,k] )

#define NN 2048
#define CC 32

__device__ __forceinline__ void g2l16(const float* g, float* l) {
  __builtin_amdgcn_global_load_lds((const __attribute__((address_space(1))) void*)g,
                                   (__attribute__((address_space(3))) void*)l, 16, 0, 0);
}

// ---------- Kernel 0: I[c] = 1 / sum_n exp(R[n][c]) ----------
__global__ void caps_stats(const float* __restrict__ R, float* __restrict__ I) {
  const int c = blockIdx.x;   // 0..31
  const int t = threadIdx.x;  // 0..255
  __shared__ float red[256];
  float s = 0.f;
#pragma unroll
  for (int i = 0; i < 8; ++i) s += expf(R[(size_t)(t + i * 256) * CC + c]);
  red[t] = s;
  __syncthreads();
  for (int h = 128; h >= 1; h >>= 1) {
    if (t < h) red[t] += red[t + h];
    __syncthreads();
  }
  if (t == 0) I[c] = 1.0f / red[0];
}

// ---------- Kernel 1: barrier-free pipelined contraction ----------
// grid 512: chunk = bid&63 (32 n), cq = bid>>6 (4 c). XCD = bid%8 = chunk%8 ->
// the 8 cq-blocks of a chunk share an XCD (x L2-resident). block 512 = 8 waves;
// 64KB LDS -> 2 blocks/CU. ALL staging is wave-private: wave ws owns n = n0+ws*4..+4.
//   W: per n, 128 granules (2 g2l16) into wave buf[2]; slot S holds granule
//      g = S ^ bit0(S2^S4) ^ bit1(S3) ^ bit2(S4)  (inverse of S = g ^ (j>>1)).
//   x: per n, 64 granules (1 g2l16, per-lane src does k<->b transpose);
//      slot S = G ^ ((G>>4)<<1) (bo-spread swizzle), G = b*2+kq.
// Main loop: counted s_waitcnt vmcnt(2) (never 0 until last), NO __syncthreads.
// NO occupancy attributes: measured (R4/R6) they clamp VGPR to 64 -> 60MB spill.
__global__ void __launch_bounds__(512) caps_main(const float* __restrict__ x,
                                                 const float* __restrict__ W,
                                                 const float* __restrict__ R,
                                                 const float* __restrict__ I,
                                                 float* __restrict__ P) {
  const int bid = blockIdx.x;
  const int cq = bid >> 6;
  const int chunk = bid & 63;
  const int n0 = chunk * 32;
  const int tid = threadIdx.x;
  const int ws = tid >> 6;
  const int lane = tid & 63;
  const int j = lane & 15;
  const int bo = lane >> 4;

  extern __shared__ float smem[];   // 16384 floats (64 KB)
  float* ldsW = smem;               // [8 waves][2 bufs][512]
  float* ldsX = smem + 8192;        // [8 waves][4 n][256]
  float* wW = ldsW + ws * 1024;
  float* wX = ldsX + ws * 1024;
  const int nw = n0 + ws * 4;       // this wave's first n

  // --- prologue: wave-private async staging (no barrier anywhere before loop) ---
  auto stageW = [&](int nl, int buf) {
#pragma unroll
    for (int i = 0; i < 2; ++i) {
      int S = i * 64 + lane;
      int g = S ^ (((S >> 2) ^ (S >> 4)) & 1) ^ (((S >> 3) & 1) << 1) ^ (((S >> 4) & 1) << 2);
      g2l16(W + (size_t)(nw + nl) * 4096 + cq * 512 + g * 4, wW + buf * 512 + i * 256);
    }
  };
  stageW(0, 0);
  {
    int g2 = lane ^ ((lane >> 4) << 1);   // slot 'lane' holds granule g2
    int b = g2 >> 1, kq = g2 & 1;
    const float* xs = x + (size_t)b * (NN * 8) + kq * 4;
#pragma unroll
    for (int nl = 0; nl < 4; ++nl)
      g2l16(xs + (size_t)(nw + nl) * 8, wX + nl * 256);
  }
  // routing weights (vmem loads here all drain at the first counted wait)
  float rv[4][4];
  {
    float4 iv = *(const float4*)(I + cq * 4);
#pragma unroll
    for (int nl = 0; nl < 4; ++nl) {
      float4 rq = *(const float4*)(R + (size_t)(nw + nl) * CC + cq * 4);
      rv[nl][0] = expf(rq.x) * iv.x;
      rv[nl][1] = expf(rq.y) * iv.y;
      rv[nl][2] = expf(rq.z) * iv.z;
      rv[nl][3] = expf(rq.w) * iv.w;
    }
  }

  float acc[4][8];
#pragma unroll
  for (int a = 0; a < 4; ++a)
#pragma unroll
    for (int b = 0; b < 8; ++b) acc[a][b] = 0.f;

  const int jsw = j >> 1;

  auto compute = [&](int nl, int buf) {
    const float* Wn = wW + buf * 512;
    const float* Xn = wX + nl * 256;
#pragma unroll
    for (int kh = 0; kh < 2; ++kh) {
      float4 xv[8];
#pragma unroll
      for (int bi = 0; bi < 8; ++bi) {
        int G = (bo * 8 + bi) * 2 + kh;
        int S = G ^ ((G >> 4) << 1);
        xv[bi] = *(const float4*)(Xn + S * 4);
      }
#pragma unroll
      for (int ci = 0; ci < 4; ++ci) {
        int slot = (ci * 32 + j * 2 + kh) ^ jsw;
        float4 wf = *(const float4*)(Wn + slot * 4);
        float rvv = rv[nl][ci];
        float w0 = wf.x * rvv, w1 = wf.y * rvv, w2 = wf.z * rvv, w3 = wf.w * rvv;
#pragma unroll
        for (int bi = 0; bi < 8; ++bi) {
          float a = acc[ci][bi];
          a = fmaf(w0, xv[bi].x, a);
          a = fmaf(w1, xv[bi].y, a);
          a = fmaf(w2, xv[bi].z, a);
          a = fmaf(w3, xv[bi].w, a);
          acc[ci][bi] = a;
        }
      }
    }
  };

  // --- pipelined loop: stage(k+1) issued before compute(k); counted waits;
  //     sched_barrier(0) fences per rule #18 and to pin WAR ordering ---
  stageW(1, 1);
  asm volatile("s_waitcnt vmcnt(2)" ::: "memory");   // x + W n0 landed
  __builtin_amdgcn_sched_barrier(0);
  compute(0, 0);
  __builtin_amdgcn_sched_barrier(0);                 // keep stage(2) below compute(0) reads
  stageW(2, 0);
  asm volatile("s_waitcnt vmcnt(2)" ::: "memory");   // W n1 landed
  __builtin_amdgcn_sched_barrier(0);
  compute(1, 1);
  __builtin_amdgcn_sched_barrier(0);
  stageW(3, 1);
  asm volatile("s_waitcnt vmcnt(2)" ::: "memory");   // W n2 landed
  __builtin_amdgcn_sched_barrier(0);
  compute(2, 0);
  asm volatile("s_waitcnt vmcnt(0)" ::: "memory");   // W n3 landed
  __builtin_amdgcn_sched_barrier(0);
  compute(3, 1);

  // --- epilogue: dump into wave-OWN regions (in-wave DS order makes it safe),
  //     single barrier, then block-sum + coalesced P write ---
#pragma unroll
  for (int ci = 0; ci < 4; ++ci)
#pragma unroll
    for (int bi = 0; bi < 8; ++bi) {
      int cell = (ci * 8 + bi) * 64 + lane;  // ci<2 <=> cell<1024
      float* dst = (ci < 2) ? (ldsW + ws * 1024 + cell)
                            : (ldsX + ws * 1024 + (cell - 1024));
      *dst = acc[ci][bi];
    }
  __syncthreads();
  {
    const int t4 = tid * 4;
    const bool lo = (t4 < 1024);
    float4 ssum = make_float4(0.f, 0.f, 0.f, 0.f);
#pragma unroll
    for (int w = 0; w < 8; ++w) {
      const float* src = lo ? (ldsW + w * 1024 + t4) : (ldsX + w * 1024 + (t4 - 1024));
      float4 v = *(const float4*)src;
      ssum.x += v.x; ssum.y += v.y; ssum.z += v.z; ssum.w += v.w;
    }
    *(float4*)(P + (size_t)bid * 2048 + t4) = ssum;
  }
}

// ---------- Kernel 2: cross-chunk reduce + squash ----------
// P[bid = cq*64 + ch][cell = (ci*8+bi)*64 + bo*16 + j]
__global__ void caps_reduce(const float* __restrict__ P, float* __restrict__ out) {
  const int g = blockIdx.x * 256 + threadIdx.x;  // b*512 + c*16 + j
  const int j = g & 15;
  const int c = (g >> 4) & 31;
  const int b = g >> 9;
  const int bo = b >> 3, bi = b & 7;
  const int cq = c >> 2, ci = c & 3;
  const int idx = (ci * 8 + bi) * 64 + (bo * 16 + j);
  const float* Pq = P + (size_t)cq * 64 * 2048 + idx;

  float s = 0.f;
#pragma unroll 16
  for (int ch = 0; ch < 64; ++ch) {
    s += Pq[(size_t)ch * 2048];
  }
  float sq = s * s;
  sq += __shfl_xor(sq, 8, 16);
  sq += __shfl_xor(sq, 4, 16);
  sq += __shfl_xor(sq, 2, 16);
  sq += __shfl_xor(sq, 1, 16);
  float ss = sq + 1e-7f;
  float scale = sqrtf(ss) / (1.0f + ss);
  out[g] = scale * s;
}

extern "C" void kernel_launch(void* const* d_in, const int* in_sizes, int n_in,
                              void* d_out, int out_size, void* d_ws, size_t ws_size,
                              hipStream_t stream) {
  const float* x = (const float*)d_in[0];   // 32*2048*8
  const float* W = (const float*)d_in[1];   // 2048*32*16*8
  const float* R = (const float*)d_in[2];   // 2048*32
  float* out = (float*)d_out;               // 32*32*16

  float* I = (float*)d_ws;                  // 32 floats (pad to 64)
  float* P = (float*)d_ws + 64;             // 512*2048 floats (4 MB)

  hipFuncSetAttribute((const void*)caps_main,
                      hipFuncAttributeMaxDynamicSharedMemorySize, 65536);

  caps_stats<<<32, 256, 0, stream>>>(R, I);
  caps_main<<<512, 512, 65536, stream>>>(x, W, R, I, P);
  caps_reduce<<<64, 256, 0, stream>>>(P, out);
}